// Round 3
// baseline (1396.650 us; speedup 1.0000x reference)
//
#include <hip/hip_runtime.h>
#include <hip/hip_bf16.h>

#define IDIM 80
#define HDIM 512
#define ODIM 128
#define G5   5
#define BB   512
#define TT   512
#define PDIM 1285          // G*2*ODIM + G
#define GDIM 1536          // 3*HDIM
#define NB   16            // persistent blocks
#define JPB  32            // h-elements per block (512/16); rows = 3*JPB

typedef unsigned u32x4 __attribute__((ext_vector_type(4)));

// xp[b,g] = dot(ys[b,T-1,:], W_ih[g,:]) + b_ih[g]   grid (48 row-groups, 8 b-groups)
__global__ void __launch_bounds__(512) xp_kernel(
    const float* __restrict__ ys, const float* __restrict__ W_ih,
    const float* __restrict__ b_ih, float* __restrict__ xp)
{
  __shared__ float wih[32 * 82];
  __shared__ float bihs[32];
  const int tid = threadIdx.x;
  const int g0 = blockIdx.x * 32;
  const int b0 = blockIdx.y * 64;
  for (int idx = tid; idx < 32 * IDIM; idx += 512) {
    int g = idx / IDIM, f = idx % IDIM;
    wih[g * 82 + f] = W_ih[(size_t)(g0 + g) * IDIM + f];
  }
  if (tid < 32) bihs[tid] = b_ih[g0 + tid];
  __syncthreads();
  const int g = tid & 31, bo = tid >> 5;           // 16 b-slots per pass
  for (int pass = 0; pass < 4; ++pass) {
    int b = b0 + pass * 16 + bo;
    const float* yrow = ys + ((size_t)b * TT + (TT - 1)) * IDIM;
    float acc = bihs[g];
    #pragma unroll
    for (int f = 0; f < IDIM; f += 2) {
      float2 wv = *(const float2*)(&wih[g * 82 + f]);
      float2 yv = *(const float2*)(&yrow[f]);
      acc += wv.x * yv.x + wv.y * yv.y;
    }
    xp[(size_t)b * GDIM + g0 + g] = acc;
  }
}

// Persistent recurrence, 16 blocks, no grid barrier.
// Thread (wave,r4,c==0) of block nb produces ALL THREE gate pre-activations
// for h-element jglob = nb*32 + wave*4 + r4, stored as three tagged 8-byte
// words in one 32B chunk:  [hr|b][hz|b][hn|b][pad].
// Every thread polls exactly one chunk (its own j = tid) with a 16B+8B
// uncached load pair — per-8B-word atomicity is guaranteed by the 8B atomic
// stores, so no 16B tearing assumption is needed.
// WAR on the parity double-buffer is safe: a tag-b store happens only after
// its block consumed all of step b-1, whose producers consumed all of b-2,
// so slot[b&1] is globally dead before overwrite.
__global__ void __launch_bounds__(512) gru_kernel(
    const float* __restrict__ W_hh, const float* __restrict__ b_hh,
    const float* __restrict__ xp, unsigned long long* __restrict__ ghT,
    float* __restrict__ last)
{
  const int tid  = threadIdx.x;
  const int nb   = blockIdx.x;
  const int lane = tid & 63;
  const int wave = tid >> 6;
  const int r4   = lane >> 4;          // 0..3
  const int c    = lane & 15;          // 0..15 : 32-col chunk
  const int jj   = wave * 4 + r4;      // 0..31 block-local element
  const int jglob = nb * JPB + jj;

  __shared__ float hs[2][16 * 36];     // h double-buffered, padded stride 36

  // 96 weights/thread: 3 gate rows x 32 cols
  float4 wreg[3][8];
  float bias[3];
  #pragma unroll
  for (int g = 0; g < 3; ++g) {
    const float* wrow = W_hh + ((size_t)(g * HDIM + jglob)) * HDIM + c * 32;
    #pragma unroll
    for (int i = 0; i < 8; ++i) wreg[g][i] = ((const float4*)wrow)[i];
    bias[g] = b_hh[g * HDIM + jglob];
  }

  for (int w = tid; w < 16 * 36; w += 512) { hs[0][w] = 0.f; hs[1][w] = 0.f; }
  __syncthreads();

  const int j = tid;                            // consumer element
  const int jphys = (j >> 5) * 36 + (j & 31);

  for (int b = 0; b < BB; ++b) {
    // xp: plain cached loads (written by xp_kernel; dispatch boundary = visible)
    const float* xpb = xp + (size_t)b * GDIM;
    float xr = xpb[j];
    float xz = xpb[512 + j];
    float xn = xpb[1024 + j];

    // h chunk (32 floats) read ONCE, reused for all 3 gate passes
    const float* hbase = &hs[b & 1][c * 36];
    float4 h4[8];
    #pragma unroll
    for (int i = 0; i < 8; ++i) h4[i] = ((const float4*)hbase)[i];

    unsigned long long* chunk = ghT + (size_t)(b & 1) * (HDIM * 4);
    #pragma unroll
    for (int g = 0; g < 3; ++g) {
      float a0 = 0.f, a1 = 0.f, a2 = 0.f, a3 = 0.f;
      #pragma unroll
      for (int i = 0; i < 8; ++i) {
        a0 += wreg[g][i].x * h4[i].x; a1 += wreg[g][i].y * h4[i].y;
        a2 += wreg[g][i].z * h4[i].z; a3 += wreg[g][i].w * h4[i].w;
      }
      float acc = (a0 + a1) + (a2 + a3);
      acc += __shfl_xor(acc, 1);
      acc += __shfl_xor(acc, 2);
      acc += __shfl_xor(acc, 4);
      acc += __shfl_xor(acc, 8);
      if (c == 0) {
        union { float f; unsigned u; } cv; cv.f = acc + bias[g];
        unsigned long long pv = ((unsigned long long)(unsigned)b << 32) | cv.u;
        __hip_atomic_store(&chunk[jglob * 4 + g], pv,
                           __ATOMIC_RELAXED, __HIP_MEMORY_SCOPE_AGENT);
      }
    }

    // poll my chunk: one 16B + one 8B uncached load per iteration
    float hr, hz, hn;
    {
      unsigned long long addr = (unsigned long long)(&chunk[(size_t)j * 4]);
      u32x4 w01; unsigned long long w2;
      int guard = 0; bool ok;
      do {
        asm volatile(
          "global_load_dwordx4 %0, %2, off sc0 sc1\n\t"
          "global_load_dwordx2 %1, %2, off offset:16 sc0 sc1\n\t"
          "s_waitcnt vmcnt(0)"
          : "=&v"(w01), "=&v"(w2) : "v"(addr) : "memory");
        ok = (w01.y == (unsigned)b) & (w01.w == (unsigned)b)
           & ((unsigned)(w2 >> 32) == (unsigned)b);
      } while (!ok && ++guard < (1 << 20));     // bounded: fail, don't hang
      union { unsigned u; float f; } c0, c1, c2;
      c0.u = w01.x; c1.u = w01.z; c2.u = (unsigned)w2;
      hr = c0.f; hz = c1.f; hn = c2.f;
    }

    float h_old = hs[b & 1][jphys];
    float r = 1.f / (1.f + __expf(-(xr + hr)));
    float z = 1.f / (1.f + __expf(-(xz + hz)));
    float e2 = __expf(2.f * (xn + r * hn));
    float n = 1.f - 2.f / (e2 + 1.f);           // tanh, overflow-safe
    float hnew = (1.f - z) * n + z * h_old;
    hs[(b + 1) & 1][jphys] = hnew;              // write OTHER buffer: no WAR
    if (nb == 0) last[(size_t)b * HDIM + j] = hnew;
    __syncthreads();                            // h[b+1] complete for next step
  }
}

// params[b,p] = dot(last[b,:], W_proj[p,:]) + b_proj[p]  (64x64 tiles, K=512)
__global__ void __launch_bounds__(256) proj_kernel(
    const float* __restrict__ last, const float* __restrict__ W_proj,
    const float* __restrict__ b_proj, float* __restrict__ params)
{
  const int tid = threadIdx.x;
  const int pt = blockIdx.x * 64;
  const int bt = blockIdx.y * 64;
  __shared__ float As[16 * 65];
  __shared__ float Bs[16 * 65];
  const int tb = (tid >> 4) * 4;
  const int tp = (tid & 15) * 4;
  float acc[4][4] = {};
  for (int k0 = 0; k0 < HDIM; k0 += 16) {
    #pragma unroll
    for (int i = 0; i < 4; ++i) {
      int idx = tid + i * 256;
      int k = idx & 15, m = idx >> 4;
      As[k * 65 + m] = last[(size_t)(bt + m) * HDIM + k0 + k];
      int gp = pt + m;
      Bs[k * 65 + m] = (gp < PDIM) ? W_proj[(size_t)gp * HDIM + k0 + k] : 0.f;
    }
    __syncthreads();
    #pragma unroll
    for (int k = 0; k < 16; ++k) {
      float a[4], bv[4];
      #pragma unroll
      for (int i = 0; i < 4; ++i) a[i] = As[k * 65 + tb + i];
      #pragma unroll
      for (int i = 0; i < 4; ++i) bv[i] = Bs[k * 65 + tp + i];
      #pragma unroll
      for (int i = 0; i < 4; ++i)
        #pragma unroll
        for (int jj = 0; jj < 4; ++jj) acc[i][jj] += a[i] * bv[jj];
    }
    __syncthreads();
  }
  #pragma unroll
  for (int i = 0; i < 4; ++i) {
    int gb = bt + tb + i;
    #pragma unroll
    for (int jj = 0; jj < 4; ++jj) {
      int gp = pt + tp + jj;
      if (gp < PDIM) params[(size_t)gb * PDIM + gp] = acc[i][jj] + b_proj[gp];
    }
  }
}

// samples[b,o] = sum_i w_i * (mu_i + (var_i+1e-6)*eps[i,b,o])
__global__ void mix_kernel(const float* __restrict__ params,
                           const float* __restrict__ eps,
                           float* __restrict__ out)
{
  int b = blockIdx.x, o = threadIdx.x;
  const float* pr = params + (size_t)b * PDIM;
  float s = 0.f;
  #pragma unroll
  for (int i = 0; i < G5; ++i) {
    float mu  = pr[i * ODIM + o];
    float var = pr[2 * i * ODIM + o] + 1e-6f;
    float w   = pr[2 * G5 * ODIM + i];
    float e   = eps[((size_t)i * BB + b) * ODIM + o];
    s += w * (mu + var * e);
  }
  out[(size_t)b * ODIM + o] = s;
}

extern "C" void kernel_launch(void* const* d_in, const int* in_sizes, int n_in,
                              void* d_out, int out_size, void* d_ws, size_t ws_size,
                              hipStream_t stream) {
  const float* ys     = (const float*)d_in[0];
  const float* W_ih   = (const float*)d_in[1];
  const float* W_hh   = (const float*)d_in[2];
  const float* b_ih   = (const float*)d_in[3];
  const float* b_hh   = (const float*)d_in[4];
  const float* W_proj = (const float*)d_in[5];
  const float* b_proj = (const float*)d_in[6];
  const float* eps    = (const float*)d_in[7];
  float* out = (float*)d_out;

  // workspace layout
  char* ws = (char*)d_ws;
  unsigned long long* ghT = (unsigned long long*)ws;          // 2*512*4*8 = 32 KB
  float* xp     = (float*)(ws + 2 * HDIM * 4 * 8);            // 512*1536
  float* last   = xp + (size_t)BB * GDIM;                     // 512*512
  float* params = last + (size_t)BB * HDIM;                   // 512*1285

  hipMemsetAsync(ghT, 0xFF, 2 * HDIM * 4 * 8, stream);        // tags invalid

  dim3 gx(GDIM / 32, BB / 64);
  xp_kernel<<<gx, 512, 0, stream>>>(ys, W_ih, b_ih, xp);

  gru_kernel<<<NB, 512, 0, stream>>>(W_hh, b_hh, xp, ghT, last);

  dim3 gc((PDIM + 63) / 64, BB / 64);
  proj_kernel<<<gc, 256, 0, stream>>>(last, W_proj, b_proj, params);

  mix_kernel<<<BB, ODIM, 0, stream>>>(params, eps, out);
}

// Round 6
// 1277.241 us; speedup vs baseline: 1.0935x; 1.0935x over previous
//
#include <hip/hip_runtime.h>
#include <hip/hip_bf16.h>

#define IDIM 80
#define HDIM 512
#define ODIM 128
#define G5   5
#define BB   512
#define TT   512
#define PDIM 1285          // G*2*ODIM + G
#define GDIM 1536          // 3*HDIM
#define NW   16            // worker blocks
#define JPB  32            // h-elements per block (512/16)

// xp[b,g] = dot(ys[b,T-1,:], W_ih[g,:]) + b_ih[g]
__global__ void __launch_bounds__(512) xp_kernel(
    const float* __restrict__ ys, const float* __restrict__ W_ih,
    const float* __restrict__ b_ih, float* __restrict__ xp)
{
  __shared__ float wih[32 * 82];
  __shared__ float bihs[32];
  const int tid = threadIdx.x;
  const int g0 = blockIdx.x * 32;
  const int b0 = blockIdx.y * 64;
  for (int idx = tid; idx < 32 * IDIM; idx += 512) {
    int g = idx / IDIM, f = idx % IDIM;
    wih[g * 82 + f] = W_ih[(size_t)(g0 + g) * IDIM + f];
  }
  if (tid < 32) bihs[tid] = b_ih[g0 + tid];
  __syncthreads();
  const int g = tid & 31, bo = tid >> 5;
  for (int pass = 0; pass < 4; ++pass) {
    int b = b0 + pass * 16 + bo;
    const float* yrow = ys + ((size_t)b * TT + (TT - 1)) * IDIM;
    float acc = bihs[g];
    #pragma unroll
    for (int f = 0; f < IDIM; f += 2) {
      float2 wv = *(const float2*)(&wih[g * 82 + f]);
      float2 yv = *(const float2*)(&yrow[f]);
      acc += wv.x * yv.x + wv.y * yv.y;
    }
    xp[(size_t)b * GDIM + g0 + g] = acc;
  }
}

// Persistent GRU recurrence: 16 blocks, h-broadcast exchange, AGENT scope
// only (round-2-proven visibility). Producer thread (c==0) of element jglob
// computes all 3 gate dots, applies the gates, and publishes h_new as ONE
// tagged 8-byte word (step<<32 | f32 bits). Every thread polls one word.
// Parity double-buffer WAR-safe by induction: a tag-b store implies its
// block consumed all of b-1, whose producers consumed all of b-2 (the slot
// being overwritten).
__global__ void __launch_bounds__(512) gru_kernel(
    const float* __restrict__ W_hh, const float* __restrict__ b_hh,
    const float* __restrict__ xp, unsigned long long* __restrict__ hw,
    float* __restrict__ last)
{
  const int nb   = blockIdx.x;                   // 0..15
  const int tid  = threadIdx.x;
  const int lane = tid & 63;
  const int wave = tid >> 6;
  const int r4   = lane >> 4;                    // 0..3
  const int c    = lane & 15;                    // 0..15 : 32-col chunk
  const int jj   = wave * 4 + r4;                // 0..31
  const int jglob = nb * JPB + jj;
  const bool prod = (c == 0);

  __shared__ float hs[2][16 * 36];               // padded h double buffer

  // 96 weights/thread: 3 gate rows (jglob, 512+jglob, 1024+jglob), 32 cols
  float4 wreg[3][8];
  float bias[3];
  #pragma unroll
  for (int g = 0; g < 3; ++g) {
    const float* wrow = W_hh + ((size_t)(g * HDIM + jglob)) * HDIM + c * 32;
    #pragma unroll
    for (int i = 0; i < 8; ++i) wreg[g][i] = ((const float4*)wrow)[i];
    bias[g] = b_hh[g * HDIM + jglob];
  }

  for (int w = tid; w < 16 * 36; w += 512) { hs[0][w] = 0.f; hs[1][w] = 0.f; }
  __syncthreads();

  const int j = tid;                             // element this thread polls
  const int jphys = (j >> 5) * 36 + (j & 31);
  const int pphys = (jglob >> 5) * 36 + (jglob & 31);

  for (int b = 0; b < BB; ++b) {
    // producer inputs first: cached loads overlap the matvec
    float xr = 0.f, xz = 0.f, xn = 0.f;
    if (prod) {
      const float* xpb = xp + (size_t)b * GDIM;  // plain cached (round-3-proven)
      xr = xpb[jglob];
      xz = xpb[512 + jglob];
      xn = xpb[1024 + jglob];
    }

    // h chunk (32 floats) read once from LDS, reused for 3 gate rows
    const float* hbase = &hs[b & 1][c * 36];
    float4 h4[8];
    #pragma unroll
    for (int i = 0; i < 8; ++i) h4[i] = ((const float4*)hbase)[i];

    float gsum[3];
    #pragma unroll
    for (int g = 0; g < 3; ++g) {
      float a0 = 0.f, a1 = 0.f, a2 = 0.f, a3 = 0.f;
      #pragma unroll
      for (int i = 0; i < 8; ++i) {
        a0 += wreg[g][i].x * h4[i].x; a1 += wreg[g][i].y * h4[i].y;
        a2 += wreg[g][i].z * h4[i].z; a3 += wreg[g][i].w * h4[i].w;
      }
      float acc = (a0 + a1) + (a2 + a3);
      acc += __shfl_xor(acc, 1);
      acc += __shfl_xor(acc, 2);
      acc += __shfl_xor(acc, 4);
      acc += __shfl_xor(acc, 8);
      gsum[g] = acc;
    }

    unsigned long long* slot = hw + (size_t)(b & 1) * HDIM;

    if (prod) {
      float h_old = hs[b & 1][pphys];
      float r = 1.f / (1.f + __expf(-(xr + gsum[0] + bias[0])));
      float z = 1.f / (1.f + __expf(-(xz + gsum[1] + bias[1])));
      float e2 = __expf(2.f * (xn + r * (gsum[2] + bias[2])));
      float n = 1.f - 2.f / (e2 + 1.f);          // tanh, overflow-safe
      float hnew = (1.f - z) * n + z * h_old;
      last[(size_t)b * HDIM + jglob] = hnew;     // owner writes output row
      union { float f; unsigned u; } cv; cv.f = hnew;
      unsigned long long pv = ((unsigned long long)(unsigned)b << 32) | cv.u;
      __hip_atomic_store(&slot[jglob], pv, __ATOMIC_RELAXED,
                         __HIP_MEMORY_SCOPE_AGENT);          // round-2-proven
    }

    // every thread consumes one h_new word (AGENT load, round-2-proven)
    unsigned long long v;
    int guard = 0;
    do {
      v = __hip_atomic_load(&slot[j], __ATOMIC_RELAXED,
                            __HIP_MEMORY_SCOPE_AGENT);
    } while ((unsigned)(v >> 32) != (unsigned)b && ++guard < (1 << 20));

    union { unsigned u; float f; } hv; hv.u = (unsigned)v;
    hs[(b + 1) & 1][jphys] = hv.f;
    __syncthreads();                             // h(b+1) complete
  }
}

// params[b,p] = dot(last[b,:], W_proj[p,:]) + b_proj[p]  (64x64 tiles, K=512)
__global__ void __launch_bounds__(256) proj_kernel(
    const float* __restrict__ last, const float* __restrict__ W_proj,
    const float* __restrict__ b_proj, float* __restrict__ params)
{
  const int tid = threadIdx.x;
  const int pt = blockIdx.x * 64;
  const int bt = blockIdx.y * 64;
  __shared__ float As[16 * 65];
  __shared__ float Bs[16 * 65];
  const int tb = (tid >> 4) * 4;
  const int tp = (tid & 15) * 4;
  float acc[4][4] = {};
  for (int k0 = 0; k0 < HDIM; k0 += 16) {
    #pragma unroll
    for (int i = 0; i < 4; ++i) {
      int idx = tid + i * 256;
      int k = idx & 15, m = idx >> 4;
      As[k * 65 + m] = last[(size_t)(bt + m) * HDIM + k0 + k];
      int gp = pt + m;
      Bs[k * 65 + m] = (gp < PDIM) ? W_proj[(size_t)gp * HDIM + k0 + k] : 0.f;
    }
    __syncthreads();
    #pragma unroll
    for (int k = 0; k < 16; ++k) {
      float a[4], bv[4];
      #pragma unroll
      for (int i = 0; i < 4; ++i) a[i] = As[k * 65 + tb + i];
      #pragma unroll
      for (int i = 0; i < 4; ++i) bv[i] = Bs[k * 65 + tp + i];
      #pragma unroll
      for (int i = 0; i < 4; ++i)
        #pragma unroll
        for (int jj = 0; jj < 4; ++jj) acc[i][jj] += a[i] * bv[jj];
    }
    __syncthreads();
  }
  #pragma unroll
  for (int i = 0; i < 4; ++i) {
    int gb = bt + tb + i;
    #pragma unroll
    for (int jj = 0; jj < 4; ++jj) {
      int gp = pt + tp + jj;
      if (gp < PDIM) params[(size_t)gb * PDIM + gp] = acc[i][jj] + b_proj[gp];
    }
  }
}

// samples[b,o] = sum_i w_i * (mu_i + (var_i+1e-6)*eps[i,b,o])
__global__ void mix_kernel(const float* __restrict__ params,
                           const float* __restrict__ eps,
                           float* __restrict__ out)
{
  int b = blockIdx.x, o = threadIdx.x;
  const float* pr = params + (size_t)b * PDIM;
  float s = 0.f;
  #pragma unroll
  for (int i = 0; i < G5; ++i) {
    float mu  = pr[i * ODIM + o];
    float var = pr[2 * i * ODIM + o] + 1e-6f;
    float w   = pr[2 * G5 * ODIM + i];
    float e   = eps[((size_t)i * BB + b) * ODIM + o];
    s += w * (mu + var * e);
  }
  out[(size_t)b * ODIM + o] = s;
}

extern "C" void kernel_launch(void* const* d_in, const int* in_sizes, int n_in,
                              void* d_out, int out_size, void* d_ws, size_t ws_size,
                              hipStream_t stream) {
  const float* ys     = (const float*)d_in[0];
  const float* W_ih   = (const float*)d_in[1];
  const float* W_hh   = (const float*)d_in[2];
  const float* b_ih   = (const float*)d_in[3];
  const float* b_hh   = (const float*)d_in[4];
  const float* W_proj = (const float*)d_in[5];
  const float* b_proj = (const float*)d_in[6];
  const float* eps    = (const float*)d_in[7];
  float* out = (float*)d_out;

  // workspace layout
  char* ws = (char*)d_ws;
  unsigned long long* hw = (unsigned long long*)ws;           // 2*512*8 = 8 KB
  float* xp     = (float*)(ws + 2 * HDIM * 8 + 256);          // 512*1536
  float* last   = xp + (size_t)BB * GDIM;                     // 512*512
  float* params = last + (size_t)BB * HDIM;                   // 512*1285

  hipMemsetAsync(hw, 0xFF, 2 * HDIM * 8, stream);             // tags invalid

  dim3 gx(GDIM / 32, BB / 64);
  xp_kernel<<<gx, 512, 0, stream>>>(ys, W_ih, b_ih, xp);

  gru_kernel<<<NW, 512, 0, stream>>>(W_hh, b_hh, xp, hw, last);

  dim3 gc((PDIM + 63) / 64, BB / 64);
  proj_kernel<<<gc, 256, 0, stream>>>(last, W_proj, b_proj, params);

  mix_kernel<<<BB, ODIM, 0, stream>>>(params, eps, out);
}